// Round 7
// baseline (213.846 us; speedup 1.0000x reference)
//
#include <hip/hip_runtime.h>
#include <hip/hip_bf16.h>

typedef __attribute__((ext_vector_type(8))) __bf16 bf16x8;
typedef __attribute__((ext_vector_type(4))) float f32x4;

#define NB 32768
#define HDIM 512
#define KDIM 1024

struct WPtrs { const float* wi[4]; const float* wh[4]; };
struct BPtrs { const float* bi[4]; const float* bh[4]; };

__device__ __forceinline__ float fsigmoid(float x) {
  return 1.0f / (1.0f + __expf(-x));
}
__device__ __forceinline__ float ftanh(float x) {
  return 2.0f / (1.0f + __expf(-2.0f * x)) - 1.0f;
}
__device__ __forceinline__ bf16x8 pack8(float4 a, float4 b) {
  bf16x8 r;
  r[0] = (__bf16)a.x; r[1] = (__bf16)a.y; r[2] = (__bf16)a.z; r[3] = (__bf16)a.w;
  r[4] = (__bf16)b.x; r[5] = (__bf16)b.y; r[6] = (__bf16)b.z; r[7] = (__bf16)b.w;
  return r;
}
__device__ __forceinline__ void gll16(const void* g, void* l) {
  __builtin_amdgcn_global_load_lds(
      (const __attribute__((address_space(1))) void*)g,
      (__attribute__((address_space(3))) void*)l, 16, 0, 0);
}
#define MFMA16(A, B, C) \
  C = __builtin_amdgcn_mfma_f32_16x16x32_bf16(A, B, C, 0, 0, 0)
#define SBAR() __builtin_amdgcn_s_barrier()
#define SCHED0() __builtin_amdgcn_sched_barrier(0)

// ====================== prep (unchanged, verified r1-r5) ======================
__global__ void pack_bias_kernel(BPtrs p, float* __restrict__ bias) {
  int idx = blockIdx.x * 256 + threadIdx.x;  // 0..2047
  int g = idx >> 9, np = idx & 511;
  bias[idx] = p.bi[g][np] + p.bh[g][np];
}

// A = [x | h] -> bf16 [32768][1024]
__global__ void conv_a_kernel(const float* __restrict__ x,
                              const float* __restrict__ h,
                              __bf16* __restrict__ Abf) {
  const size_t N8 = (size_t)NB * KDIM / 8;
  for (size_t i = (size_t)blockIdx.x * blockDim.x + threadIdx.x; i < N8;
       i += (size_t)gridDim.x * blockDim.x) {
    size_t e = i * 8;
    int k = (int)(e & (KDIM - 1));
    size_t r = e >> 10;
    const float* s = (k < 512) ? (x + r * 512 + k) : (h + r * 512 + (k - 512));
    float4 v0 = *(const float4*)s;
    float4 v1 = *(const float4*)(s + 4);
    *(bf16x8*)(Abf + e) = pack8(v0, v1);
  }
}

// Wt[p][k], p(np,g) = (np>>6)*256 + (g>>1)*128 + ((np>>4)&3)*32 + (g&1)*16 + (np&15)
__global__ void pack_w2_kernel(WPtrs p, __bf16* __restrict__ Wt) {
  __shared__ float tile[64][65];
  const int kt = blockIdx.x;  // 16 k-tiles of 64
  const int nt = blockIdx.y;  // 8 np-tiles of 64
  const int g = blockIdx.z;   // gate
  const int k0 = kt * 64, n0 = nt * 64;
  const float* src = (k0 < 512) ? p.wi[g] : p.wh[g];
  const int k0l = (k0 < 512) ? k0 : (k0 - 512);
  const int rr = threadIdx.x >> 6;
  const int cc = threadIdx.x & 63;
#pragma unroll
  for (int pp = 0; pp < 16; ++pp) {
    int kk = pp * 4 + rr;
    tile[kk][cc] = src[(size_t)(k0l + kk) * 512 + (n0 + cc)];
  }
  __syncthreads();
#pragma unroll
  for (int pp = 0; pp < 16; ++pp) {
    int nn = pp * 4 + rr;
    int np = n0 + nn;
    int prow = (np >> 6) * 256 + ((g >> 1) << 7) + (((np >> 4) & 3) << 5) +
               ((g & 1) << 4) + (np & 15);
    Wt[(size_t)prow * KDIM + (k0 + cc)] = (__bf16)tile[cc][nn];
  }
}

// ============ persistent main: BK=32, ring-4 LDS, depth-2, barrier/tile ============
// Geometry: block 256x256, 8 waves (2M x 4N), wave = 128 rows x 64 N-cols.
// Buffer(t) = lds[(t&3)*32768]: A tile [256 rows][32 k] at +0 (16KB, row=64B),
// B tile [256 p][32 k] at +16384. Wave ds_reads are CONTIGUOUS 1KB regions
// -> bank-conflict-free by construction, no swizzle.
//
// Pipeline: tile t stages tile t+2. End-of-tile: s_waitcnt vmcnt(4) -> own
// queue = [stage(t+1) (4, issued t-1), stage(t+2) (4, issued t)]; vmcnt(4)
// retires stage(t+1), leaves stage(t+2) in flight (counted, never 0 until
// the t=126 tail). SBAR after the vmcnt EVERY tile (r6 post-mortem: the
// every-2nd-tile variant raced on odd tiles -- cross-wave stage visibility
// needs a barrier that postdates every wave's retiring vmcnt).
// Write-after-read: tile-t staging targets buf[(t+2)&3], last read during
// t-2 (all ds_reads retired at the lgkmcnt(0) before tile end), separated
// by the barriers at end of t-2 and t-1.
__global__ __launch_bounds__(512, 1) void lstm_gemm6(
    const __bf16* __restrict__ Abf, const __bf16* __restrict__ Wt,
    const float* __restrict__ cin, const float* __restrict__ bias,
    float* __restrict__ out) {
  __shared__ alignas(16) char lds[131072];
  const int tid = threadIdx.x;
  const int wid = tid >> 6;
  const int wm = wid >> 2, wn = wid & 3;
  const int lane = tid & 63;
  const int fc = lane & 15, fg = lane >> 4;

  const int bn = blockIdx.x & 7;    // one bn-panel per XCD (B stays L2-hot)
  const int bmg = blockIdx.x >> 3;  // 0..31, each covers 4 x 256 rows

  const __bf16* Bsrc = Wt + (size_t)(bn * 256) * KDIM;

  const int srow = (wid << 4) + (lane >> 2);  // 0..127
  const int skoff = (lane & 3) * 8;           // element offset (16B chunks)

  f32x4 acc[8][4];
#pragma unroll
  for (int m = 0; m < 8; ++m)
#pragma unroll
    for (int n = 0; n < 4; ++n) acc[m][n] = (f32x4){0.f, 0.f, 0.f, 0.f};

  bf16x8 a[2], b[4];

  auto stA = [&](int t) {
    if (t < 128) {
      const __bf16* s = Abf +
                        ((size_t)((bmg << 2) + (t >> 5)) * 256 + srow) * KDIM +
                        (t & 31) * 32 + skoff;
      uint32_t lb = (uint32_t)(t & 3) * 32768 + (uint32_t)wid * 1024;
      gll16(s, (void*)&lds[lb]);
      gll16(s + (size_t)128 * KDIM, (void*)&lds[lb + 8192]);
    }
  };
  auto stB = [&](int t) {
    if (t < 128) {
      const __bf16* s = Bsrc + (size_t)srow * KDIM + (t & 31) * 32 + skoff;
      uint32_t lb = (uint32_t)(t & 3) * 32768 + 16384 + (uint32_t)wid * 1024;
      gll16(s, (void*)&lds[lb]);
      gll16(s + (size_t)128 * KDIM, (void*)&lds[lb + 8192]);
    }
  };
  auto ldA = [&](uint32_t t3, int mq) -> bf16x8 {
    return *(const bf16x8*)&lds[t3 +
                                (uint32_t)(wm * 128 + mq * 16 + fc) * 64 +
                                (uint32_t)fg * 16];
  };
  auto ldB = [&](uint32_t t3, int nq) -> bf16x8 {
    return *(const bf16x8*)&lds[t3 + 16384 +
                                (uint32_t)((nq >> 1) * 128 + wn * 32 +
                                           (nq & 1) * 16 + fc) * 64 +
                                (uint32_t)fg * 16];
  };

  // hoisted epilogue constants (gate = acc column nq, verified r2-r5)
  const int np = bn * 64 + wn * 16 + fc;
  const float bi = bias[np];
  const float bf_ = bias[512 + np];
  const float bg = bias[1024 + np];
  const float bo = bias[1536 + np];
  const size_t couts = (size_t)NB * HDIM;

  // prologue: stage tiles 0 and 1; wait tile 0 (counted: leaves tile 1's 4)
  stA(0); stB(0); stA(1); stB(1);
  asm volatile("s_waitcnt vmcnt(4)" ::: "memory");
  SBAR();

#pragma unroll 4
  for (int t = 0; t < 128; ++t) {
    const uint32_t t3 = (uint32_t)(t & 3) * 32768;
    // issue order: a0, b0..b3, a1  (in-order lgkm retire)
    a[0] = ldA(t3, 0);
    b[0] = ldB(t3, 0);
    b[1] = ldB(t3, 1);
    b[2] = ldB(t3, 2);
    b[3] = ldB(t3, 3);
    a[1] = ldA(t3, 1);
#pragma unroll
    for (int mq = 0; mq < 8; ++mq) {
      // staircase: before MFMA(mq), only a(mq+1) may remain outstanding
      if (mq < 7) {
        asm volatile("s_waitcnt lgkmcnt(1)" ::: "memory");
      } else {
        asm volatile("s_waitcnt lgkmcnt(0)" ::: "memory");
      }
      SCHED0();
      __builtin_amdgcn_s_setprio(1);
      MFMA16(a[mq & 1], b[0], acc[mq][0]);
      MFMA16(a[mq & 1], b[1], acc[mq][1]);
      MFMA16(a[mq & 1], b[2], acc[mq][2]);
      MFMA16(a[mq & 1], b[3], acc[mq][3]);
      __builtin_amdgcn_s_setprio(0);
      if (mq < 6) a[mq & 1] = ldA(t3, mq + 2);  // rolling prefetch
      if (mq == 2) stA(t + 2);                  // depth-2 stage, spread
      if (mq == 4) stB(t + 2);
    }
    // counted end-of-tile wait: stage(t+1) done, stage(t+2) stays in flight
    if (t < 126) {
      asm volatile("s_waitcnt vmcnt(4)" ::: "memory");
    } else if (t == 126) {
      asm volatile("s_waitcnt vmcnt(0)" ::: "memory");
    }
    SBAR();  // every tile (correctness: cross-wave stage visibility)

    // ---- inline LSTM epilogue at group end (regs+global only, no LDS) ----
    if ((t & 31) == 31) {
      const int grp = t >> 5;
#pragma unroll
      for (int mf = 0; mf < 8; ++mf) {
        const int grow0 = ((bmg << 2) + grp) * 256 + wm * 128 + mf * 16 + fg * 4;
#pragma unroll
        for (int j = 0; j < 4; ++j) {
          const size_t off = (size_t)(grow0 + j) * HDIM + np;
          float i_ = fsigmoid(acc[mf][0][j] + bi);
          float f_ = fsigmoid(acc[mf][1][j] + bf_);
          float g_ = fsigmoid(acc[mf][2][j] + bg);
          float o_ = fsigmoid(acc[mf][3][j] + bo);
          float cp = f_ * cin[off] + i_ * g_;
          out[off] = o_ * ftanh(cp);
          out[couts + off] = cp;
        }
#pragma unroll
        for (int n = 0; n < 4; ++n) acc[mf][n] = (f32x4){0.f, 0.f, 0.f, 0.f};
      }
    }
  }
}

// ====================== launch ======================
extern "C" void kernel_launch(void* const* d_in, const int* in_sizes, int n_in,
                              void* d_out, int out_size, void* d_ws,
                              size_t ws_size, hipStream_t stream) {
  const float* xin = (const float*)d_in[0];
  const float* hin = (const float*)d_in[1];
  const float* cin = (const float*)d_in[2];
  WPtrs wp;
  wp.wi[0] = (const float*)d_in[3];
  wp.wi[1] = (const float*)d_in[7];
  wp.wi[2] = (const float*)d_in[11];
  wp.wi[3] = (const float*)d_in[15];
  wp.wh[0] = (const float*)d_in[4];
  wp.wh[1] = (const float*)d_in[8];
  wp.wh[2] = (const float*)d_in[12];
  wp.wh[3] = (const float*)d_in[16];
  BPtrs bp;
  bp.bi[0] = (const float*)d_in[5];
  bp.bi[1] = (const float*)d_in[9];
  bp.bi[2] = (const float*)d_in[13];
  bp.bi[3] = (const float*)d_in[17];
  bp.bh[0] = (const float*)d_in[6];
  bp.bh[1] = (const float*)d_in[10];
  bp.bh[2] = (const float*)d_in[14];
  bp.bh[3] = (const float*)d_in[18];

  const size_t needA = (size_t)NB * KDIM * 2;    // 64 MiB
  const size_t needW = (size_t)2048 * KDIM * 2;  // 4 MiB

  __bf16* Abf = (__bf16*)d_ws;
  __bf16* Wt = (__bf16*)((char*)d_ws + needA);
  float* bias = (float*)((char*)d_ws + needA + needW);

  conv_a_kernel<<<2048, 256, 0, stream>>>(xin, hin, Abf);
  pack_w2_kernel<<<dim3(16, 8, 4), 256, 0, stream>>>(wp, Wt);
  pack_bias_kernel<<<8, 256, 0, stream>>>(bp, bias);
  lstm_gemm6<<<256, 512, 0, stream>>>(Abf, Wt, cin, bias, (float*)d_out);
}